// Round 9
// baseline (570.358 us; speedup 1.0000x reference)
//
#include <hip/hip_runtime.h>
#include <hip/hip_fp16.h>

// Problem constants (ChainGraphDQN)
#define NN 200000      // nodes
#define FIN 128        // in features
#define NE 3200000     // edges
#define NG 4096        // graphs
#define HC 16          // GCN out channels
#define D1 64          // MLP hidden
#define NM 12          // heads
#define NA 8           // actions
#define NBLK 782       // ceil(NN/256)

// Two-level binned edge layout, window-partitioned:
//   level 1: 49 coarse groups (dst>>12), contiguous lists
//   level 2: (fine bin of 64 dst nodes) x (src window) sub-lists
// fp16 h' => 2 windows of 3.2 MB each fit per-XCD L2; window phase separation
// comes from LAUNCH BOUNDARIES (round-6/7 lesson: grid.sync costs 220us/ea,
// loose phasing drifts and leaks 100 MB of HBM traffic).
#define BSHIFT 6
#define NBIN 3125                  // NN/64 exactly
#define NGRP 49                    // ceil(NN/4096)
#define CAP1 67584                 // per-group capacity; mean 65306, +9 sigma
#define CH1 8192                   // edges per level-1 block
#define NB1 391                    // ceil(NE/CH1)
#define CH2 8192                   // entries per level-2 block
#define CHK2 9                     // chunks per group = ceil(CAP1/CH2)
#define WNB 2                      // src windows
#define WW 100000                  // window width in nodes (3.2 MB of fp16 g_h)
#define CAPW 704                   // per (bin,window) capacity; mean 512, +8.5 sigma
#define SAS 17                     // s_agg row stride in floats: odd => random
                                   // rows spread over all 32 LDS banks (the
                                   // round-8 stride-16 layout put 64 lanes on
                                   // 4 banks = 16-way conflict on every atomic)

// Scratch in module __device__ globals.
__device__ __half   g_h[NN * HC];                        // 6.4 MB, holds h*dinv (fp16)
__device__ unsigned g_mid[(size_t)NGRP * CAP1];          // 13.2 MB coarse lists
__device__ unsigned g_bucket[(size_t)NBIN * WNB * CAPW]; // 17.6 MB fine lists
__device__ float    g_agg[NN * HC];                      // 12.8 MB inter-window partial
__device__ int      g_scnt1[NGRP];
__device__ int      g_scnt2[NBIN * WNB];
__device__ float    g_dinv[NN];
__device__ float    g_pooled[NG * HC];
__device__ float    g_cnt[NG];

__device__ __forceinline__ void atomAddF(float* p, float v) {
    unsafeAtomicAdd(p, v);
}

// ---------------- zero the accumulators -------------------------------------
__global__ __launch_bounds__(256) void k_zero() {
    int i = blockIdx.x * 256 + threadIdx.x;
    if (i < NGRP) g_scnt1[i] = 0;
    if (i < NBIN * WNB) g_scnt2[i] = 0;
    if (i < NG * HC) g_pooled[i] = 0.f;
    if (i < NG) g_cnt[i] = 0.f;
}

// ---------------- level-1 sort: edges -> 49 coarse dst groups ---------------
// 49 keys => fragments of ~167 edges: stores are line-dense and wave-coalesced.
// NO per-node atomics (round-5 lesson: 3.2M random atomic RMWs cost ~100 MB of
// memory-side transactions and dominated the kernel).
__global__ __launch_bounds__(1024) void k_bin1(const int* __restrict__ ei) {
    __shared__ int s_hist[NGRP];
    __shared__ int s_pref[NGRP];
    __shared__ int s_gbase[NGRP];
    __shared__ unsigned short s_perm[CH1];   // 16 KB
    int t = threadIdx.x;
    int e0 = blockIdx.x * CH1;
    int cnt = NE - e0; if (cnt > CH1) cnt = CH1;

    if (t < NGRP) s_hist[t] = 0;
    __syncthreads();
    for (int i = t; i < cnt; i += 1024)
        atomicAdd(&s_hist[ei[NE + e0 + i] >> 12], 1);
    __syncthreads();
    if (t == 0) {
        int run = 0;
        for (int b = 0; b < NGRP; b++) { s_pref[b] = run; run += s_hist[b]; }
    }
    __syncthreads();
    if (t < NGRP) {
        int c = s_hist[t];
        s_gbase[t] = c ? atomicAdd(&g_scnt1[t], c) : 0;
    }
    __syncthreads();
    if (t < NGRP) s_hist[t] = s_pref[t];     // cursor
    __syncthreads();
    for (int i = t; i < cnt; i += 1024) {
        int d = ei[NE + e0 + i];
        int pos = atomicAdd(&s_hist[d >> 12], 1);
        s_perm[pos] = (unsigned short)i;
    }
    __syncthreads();
    for (int i = t; i < cnt; i += 1024) {
        int idx = s_perm[i];
        int s = ei[e0 + idx];
        int d = ei[NE + e0 + idx];
        int grp = d >> 12;
        int gpos = s_gbase[grp] + (i - s_pref[grp]);
        if (gpos < CAP1)
            g_mid[(size_t)grp * CAP1 + gpos] =
                (unsigned)s | ((unsigned)(d & 4095) << 18);
    }
}

// ---------------- level-2 sort: group chunk -> (fine bin, src window) -------
// 128 keys over 8192 entries => ~64-edge (256 B) fragments, wave-coalesced.
__global__ __launch_bounds__(1024) void k_bin2() {
    __shared__ int            s_hist[64 * WNB];
    __shared__ int            s_scan[64 * WNB];
    __shared__ unsigned short s_pref[64 * WNB];
    __shared__ unsigned short s_gbase[64 * WNB];
    __shared__ unsigned short s_perm[CH2];   // 16 KB
    int t = threadIdx.x;
    int g = blockIdx.x / CHK2;
    int ch = blockIdx.x % CHK2;
    int total = g_scnt1[g]; if (total > CAP1) total = CAP1;
    int c0 = ch * CH2;
    if (c0 >= total) return;                 // uniform over block
    int cnt = total - c0; if (cnt > CH2) cnt = CH2;
    const unsigned* src = g_mid + (size_t)g * CAP1 + c0;

    if (t < 64 * WNB) s_hist[t] = 0;
    __syncthreads();
    for (int i = t; i < cnt; i += 1024) {
        unsigned p = src[i];
        int key = (int)((p >> 18) >> 6) * WNB + (int)((p & 0x3FFFFu) >= WW);
        atomicAdd(&s_hist[key], 1);
    }
    __syncthreads();
    // parallel exclusive scan over 128 keys (Hillis-Steele on first 128 thr)
    if (t < 128) s_scan[t] = s_hist[t];
    __syncthreads();
    for (int o = 1; o < 128; o <<= 1) {
        int u = (t >= o && t < 128) ? s_scan[t - o] : 0;
        __syncthreads();
        if (t < 128) s_scan[t] += u;
        __syncthreads();
    }
    if (t < 128) s_pref[t] = (unsigned short)(s_scan[t] - s_hist[t]);
    __syncthreads();
    if (t < 64 * WNB) {
        int c = s_hist[t];
        int gbin = (g << 6) + t / WNB;
        int w = t % WNB;
        s_gbase[t] = (unsigned short)(c ? atomicAdd(&g_scnt2[gbin * WNB + w], c) : 0);
    }
    __syncthreads();
    if (t < 64 * WNB) s_hist[t] = s_pref[t]; // cursor
    __syncthreads();
    for (int i = t; i < cnt; i += 1024) {
        unsigned p = src[i];
        int key = (int)((p >> 18) >> 6) * WNB + (int)((p & 0x3FFFFu) >= WW);
        int pos = atomicAdd(&s_hist[key], 1);
        s_perm[pos] = (unsigned short)i;
    }
    __syncthreads();
    for (int i = t; i < cnt; i += 1024) {
        unsigned p = src[s_perm[i]];
        unsigned ss = p & 0x3FFFFu;
        int d12 = (int)(p >> 18);
        int w = (int)(ss >= WW);
        int key = (d12 >> 6) * WNB + w;
        int gbin = (g << 6) + (d12 >> 6);
        int gpos = (int)s_gbase[key] + (i - (int)s_pref[key]);
        if (gpos < CAPW)
            g_bucket[(size_t)(gbin * WNB + w) * CAPW + gpos] =
                ss | ((unsigned)(d12 & 63) << 18);
    }
}

// ---------------- degrees + dinv from sorted lists (no random atomics) ------
__global__ __launch_bounds__(256) void k_degv() {
    __shared__ int s_deg[64];
    __shared__ int s_len[WNB];
    int t = threadIdx.x;
    int bk = blockIdx.x;
    if (t < 64) s_deg[t] = 0;
    if (t < WNB) {
        int l = g_scnt2[bk * WNB + t];
        s_len[t] = l < CAPW ? l : CAPW;
    }
    __syncthreads();
    for (int w = 0; w < WNB; w++) {
        const unsigned* lst = g_bucket + (size_t)(bk * WNB + w) * CAPW;
        for (int i = t; i < s_len[w]; i += 256)
            atomicAdd(&s_deg[lst[i] >> 18], 1);
    }
    __syncthreads();
    if (t < 64) g_dinv[bk * 64 + t] = rsqrtf((float)(s_deg[t] + 1));
}

// ---------------- h' = (x @ conv_w) * dinv[row] -> fp16 ---------------------
__global__ __launch_bounds__(256) void k_xw(const float* __restrict__ x,
                                            const float* __restrict__ conv_w) {
    __shared__ float s_w[FIN * HC];      // 8 KB
    __shared__ float s_x[64 * 132];      // 33.8 KB
    int t = threadIdx.x;
    for (int i = t; i < FIN * HC; i += 256) s_w[i] = conv_w[i];
    int base = blockIdx.x * 64;
    for (int idx = t; idx < 64 * FIN; idx += 256) {
        int r = idx >> 7, k = idx & 127;
        s_x[r * 132 + k] = x[(size_t)(base + r) * FIN + k];
    }
    __syncthreads();
    int c = t & 15, rg = t >> 4;
    float acc[4] = {0.f, 0.f, 0.f, 0.f};
    for (int k = 0; k < FIN; k++) {
        float w = s_w[k * HC + c];
#pragma unroll
        for (int q = 0; q < 4; q++)
            acc[q] = fmaf(s_x[(rg + 16 * q) * 132 + k], w, acc[q]);
    }
#pragma unroll
    for (int q = 0; q < 4; q++) {
        int row = base + rg + 16 * q;
        g_h[(size_t)row * HC + c] = __float2half(acc[q] * g_dinv[row]);
    }
}

// ---------------- windowed aggregate: 2 launches, fp16 gathers --------------
// Launch W gathers ONLY from window W's 3.2 MB slice of g_h => L2-resident
// (round-8: FETCH 27 MB = compulsory; confirmed). Round-9 fix: the cost left
// is CU-internal LDS-atomic serialization. 4 lanes/edge (8 B fp16x4 load each,
// lane owns 4 channels), s_agg stride 17 floats (odd => random rows spread
// over all 32 banks instead of 4), and 4-edge unroll for load ILP.
template <int W>
__global__ __launch_bounds__(256) void k_aggh(const float* __restrict__ conv_b,
                                              const int* __restrict__ batch) {
    __shared__ float s_agg[64 * SAS];    // 4.25 KB, bank-padded
    __shared__ unsigned s_lst[CAPW];     // 2.8 KB
    __shared__ float s_pool[16 * 16];
    __shared__ int s_cnt16[16];
    __shared__ int s_len;
    __shared__ int s_b0;
    int t = threadIdx.x;
    int bk = blockIdx.x;
    int base = bk << BSHIFT;

    if (t == 0) {
        int l = g_scnt2[bk * WNB + W];
        s_len = l < CAPW ? l : CAPW;
        if (W == WNB - 1) s_b0 = batch[base];
    }
    if (W == 0) {
        for (int i = t; i < 64 * SAS; i += 256) s_agg[i] = 0.f;
    } else {
        for (int i = t; i < 64 * HC; i += 256)
            s_agg[(i >> 4) * SAS + (i & 15)] = g_agg[bk * 1024 + i];
    }
    if (W == WNB - 1) {
        s_pool[t] = 0.f;
        if (t < 16) s_cnt16[t] = 0;
    }
    __syncthreads();

    int len = s_len;
    const unsigned* lst = g_bucket + (size_t)(bk * WNB + W) * CAPW;
    for (int i = t; i < len; i += 256) s_lst[i] = lst[i];
    __syncthreads();

    // 4 lanes per edge; lane q4 owns channels 4q4..4q4+3 (one 8 B load).
    int e4 = t >> 2, q4 = t & 3;
    int j = e4;
    for (; j + 192 < len; j += 256) {    // 4 edges per lane, loads batched
        unsigned p0 = s_lst[j];
        unsigned p1 = s_lst[j + 64];
        unsigned p2 = s_lst[j + 128];
        unsigned p3 = s_lst[j + 192];
        const __half2* h0 = (const __half2*)&g_h[(size_t)(p0 & 0x3FFFFu) * HC + 4 * q4];
        const __half2* h1 = (const __half2*)&g_h[(size_t)(p1 & 0x3FFFFu) * HC + 4 * q4];
        const __half2* h2 = (const __half2*)&g_h[(size_t)(p2 & 0x3FFFFu) * HC + 4 * q4];
        const __half2* h3 = (const __half2*)&g_h[(size_t)(p3 & 0x3FFFFu) * HC + 4 * q4];
        float2 a0 = __half22float2(h0[0]), b0 = __half22float2(h0[1]);
        float2 a1 = __half22float2(h1[0]), b1 = __half22float2(h1[1]);
        float2 a2 = __half22float2(h2[0]), b2 = __half22float2(h2[1]);
        float2 a3 = __half22float2(h3[0]), b3 = __half22float2(h3[1]);
        float* d0 = &s_agg[(p0 >> 18) * SAS + 4 * q4];
        float* d1 = &s_agg[(p1 >> 18) * SAS + 4 * q4];
        float* d2 = &s_agg[(p2 >> 18) * SAS + 4 * q4];
        float* d3 = &s_agg[(p3 >> 18) * SAS + 4 * q4];
        atomicAdd(d0 + 0, a0.x); atomicAdd(d0 + 1, a0.y);
        atomicAdd(d0 + 2, b0.x); atomicAdd(d0 + 3, b0.y);
        atomicAdd(d1 + 0, a1.x); atomicAdd(d1 + 1, a1.y);
        atomicAdd(d1 + 2, b1.x); atomicAdd(d1 + 3, b1.y);
        atomicAdd(d2 + 0, a2.x); atomicAdd(d2 + 1, a2.y);
        atomicAdd(d2 + 2, b2.x); atomicAdd(d2 + 3, b2.y);
        atomicAdd(d3 + 0, a3.x); atomicAdd(d3 + 1, a3.y);
        atomicAdd(d3 + 2, b3.x); atomicAdd(d3 + 3, b3.y);
    }
    for (; j < len; j += 64) {           // remainder
        unsigned p = s_lst[j];
        const __half2* h = (const __half2*)&g_h[(size_t)(p & 0x3FFFFu) * HC + 4 * q4];
        float2 a = __half22float2(h[0]), b = __half22float2(h[1]);
        float* dp = &s_agg[(p >> 18) * SAS + 4 * q4];
        atomicAdd(dp + 0, a.x); atomicAdd(dp + 1, a.y);
        atomicAdd(dp + 2, b.x); atomicAdd(dp + 3, b.y);
    }
    __syncthreads();

    if (W != WNB - 1) {
        for (int i = t; i < 64 * HC; i += 256)
            g_agg[bk * 1024 + i] = s_agg[(i >> 4) * SAS + (i & 15)];
        return;
    }

    // ---- last window: self-loop + bias + relu + fused mean-pool ----
    int c = t & 15;
#pragma unroll
    for (int qq = 0; qq < 4; qq++) {
        int ln = (t >> 4) + qq * 16;     // local node 0..63
        int node = base + ln;            // NN = 3125*64 exactly
        float di = g_dinv[node];
        float hself = __half2float(g_h[(size_t)node * HC + c]);
        float val = di * (s_agg[ln * SAS + c] + hself) + conv_b[c];
        float r = val > 0.f ? val : 0.f;
        int b = batch[node];
        int slot = b - s_b0;
        if (slot < 16) {
            atomicAdd(&s_pool[slot * 16 + c], r);
            if (c == 0) atomicAdd(&s_cnt16[slot], 1);
        } else {                         // astronomically rare
            atomAddF(&g_pooled[(size_t)b * HC + c], r);
            if (c == 0) atomAddF(&g_cnt[b], 1.f);
        }
    }
    __syncthreads();

    int slot2 = t >> 4;
    if (s_cnt16[slot2] > 0)
        atomAddF(&g_pooled[(size_t)(s_b0 + slot2) * HC + c], s_pool[t]);
    if (t < 16 && s_cnt16[t] > 0)
        atomAddF(&g_cnt[s_b0 + t], (float)s_cnt16[t]);
}

// ---------------- MLP + heads (f32 output) ----------------------------------
__global__ __launch_bounds__(256) void k_mlp(const float* __restrict__ w1,
                                             const float* __restrict__ b1,
                                             const float* __restrict__ w2,
                                             const float* __restrict__ b2,
                                             const float* __restrict__ head_w,
                                             const float* __restrict__ head_b,
                                             float* __restrict__ out) {
    __shared__ float s_w1[HC * D1];
    __shared__ float s_b1[D1];
    __shared__ float s_w2[D1 * D1];
    __shared__ float s_b2[D1];
    __shared__ float s_hw[NM * D1 * NA];
    __shared__ float s_hb[NM * NA];
    __shared__ float s_p[4][HC];
    __shared__ float s_g1[4][D1];
    __shared__ float s_g2[4][D1];

    int tid = threadIdx.x;
    for (int i = tid; i < HC * D1; i += 256) s_w1[i] = w1[i];
    for (int i = tid; i < D1; i += 256) { s_b1[i] = b1[i]; s_b2[i] = b2[i]; }
    for (int i = tid; i < D1 * D1; i += 256) s_w2[i] = w2[i];
    for (int i = tid; i < NM * D1 * NA; i += 256) s_hw[i] = head_w[i];
    for (int i = tid; i < NM * NA; i += 256) s_hb[i] = head_b[i];

    int grp = tid >> 6, lane = tid & 63;
    int g = blockIdx.x * 4 + grp;
    if (lane < HC) {
        float cc = g_cnt[g];
        s_p[grp][lane] = g_pooled[g * HC + lane] / fmaxf(cc, 1.0f);
    }
    __syncthreads();
    {
        float a = s_b1[lane];
#pragma unroll
        for (int c = 0; c < HC; c++) a = fmaf(s_p[grp][c], s_w1[c * D1 + lane], a);
        s_g1[grp][lane] = a > 0.f ? a : expm1f(a);
    }
    __syncthreads();
    {
        float a = s_b2[lane];
#pragma unroll
        for (int d = 0; d < D1; d++) a = fmaf(s_g1[grp][d], s_w2[d * D1 + lane], a);
        s_g2[grp][lane] = a > 0.f ? a : expm1f(a);
    }
    __syncthreads();
    for (int idx = lane; idx < NM * NA; idx += 64) {
        int m = idx >> 3, a = idx & 7;
        float v = s_hb[idx];
#pragma unroll
        for (int d = 0; d < D1; d++)
            v = fmaf(s_g2[grp][d], s_hw[m * (D1 * NA) + d * NA + a], v);
        out[(size_t)g * (NM * NA) + idx] = v;
    }
}

extern "C" void kernel_launch(void* const* d_in, const int* in_sizes, int n_in,
                              void* d_out, int out_size, void* d_ws, size_t ws_size,
                              hipStream_t stream) {
    const float* x      = (const float*)d_in[0];
    const int*   ei     = (const int*)d_in[1];
    const int*   batch  = (const int*)d_in[2];
    const float* conv_w = (const float*)d_in[3];
    const float* conv_b = (const float*)d_in[4];
    const float* w1     = (const float*)d_in[5];
    const float* b1     = (const float*)d_in[6];
    const float* w2     = (const float*)d_in[7];
    const float* b2     = (const float*)d_in[8];
    const float* head_w = (const float*)d_in[9];
    const float* head_b = (const float*)d_in[10];
    float* out = (float*)d_out;

    k_zero<<<NBLK, 256, 0, stream>>>();
    k_bin1<<<NB1, 1024, 0, stream>>>(ei);
    k_bin2<<<NGRP * CHK2, 1024, 0, stream>>>();
    k_degv<<<NBIN, 256, 0, stream>>>();
    k_xw<<<NN / 64, 256, 0, stream>>>(x, conv_w);
    k_aggh<0><<<NBIN, 256, 0, stream>>>(conv_b, batch);
    k_aggh<1><<<NBIN, 256, 0, stream>>>(conv_b, batch);
    k_mlp<<<NG / 4, 256, 0, stream>>>(w1, b1, w2, b2, head_w, head_b, out);
}

// Round 11
// 322.971 us; speedup vs baseline: 1.7660x; 1.7660x over previous
//
#include <hip/hip_runtime.h>
#include <hip/hip_fp16.h>

// Problem constants (ChainGraphDQN)
#define NN 200000      // nodes
#define FIN 128        // in features
#define NE 3200000     // edges
#define NG 4096        // graphs
#define HC 16          // GCN out channels
#define D1 64          // MLP hidden
#define NM 12          // heads
#define NA 8           // actions
#define NBLK 782       // ceil(NN/256)

// Two-level binned edge layout, window-partitioned, then dst-sorted per bin:
//   level 1: 49 coarse groups (dst>>12), contiguous lists
//   level 2: (fine bin of 64 dst nodes) x (src window) sub-lists
//   level 3: within each (bin,window) list, counting-sort by local dst =>
//            64 contiguous per-row segments (g_roff) => aggregation needs
//            ZERO atomics (each dst row owned by one 4-lane group, VGPR acc).
// Rounds 1-9 lesson: agg time was pinned at ~55 cyc/edge across 5 structures;
// the shared invariant was 16 LDS f32-atomic lane-ops/edge (~3.4 cyc/lane,
// lane-serialized, banking-insensitive). This version deletes them.
// Round-10 bug: wave race in k_bin3 (dinv read vs cursor overwrite) — fixed
// with a __syncthreads() between them.
#define BSHIFT 6
#define NBIN 3125                  // NN/64 exactly
#define NGRP 49                    // ceil(NN/4096)
#define CAP1 67584                 // per-group capacity; mean 65306, +9 sigma
#define CH1 8192                   // edges per level-1 block
#define NB1 391                    // ceil(NE/CH1)
#define CH2 8192                   // entries per level-2 block
#define CHK2 9                     // chunks per group = ceil(CAP1/CH2)
#define WNB 2                      // src windows
#define WW 100000                  // window width in nodes (3.2 MB of fp16 g_h)
#define CAPW 704                   // per (bin,window) capacity; mean 512, +8.5 sigma
#define SAS 17                     // s_agg row stride (epilogue staging)

// Scratch in module __device__ globals.
__device__ __half   g_h[NN * HC];                        // 6.4 MB, holds h*dinv (fp16)
__device__ unsigned g_mid[(size_t)NGRP * CAP1];          // 13.2 MB coarse lists
__device__ unsigned g_bucket[(size_t)NBIN * WNB * CAPW]; // 17.6 MB fine lists
__device__ unsigned g_bsort[(size_t)NBIN * WNB * CAPW];  // 17.6 MB dst-sorted lists
__device__ unsigned short g_roff[NBIN * WNB * 64];       // 0.8 MB row segment starts
__device__ float    g_agg[NN * HC];                      // 12.8 MB inter-window partial
__device__ int      g_scnt1[NGRP];
__device__ int      g_scnt2[NBIN * WNB];
__device__ float    g_dinv[NN];
__device__ float    g_pooled[NG * HC];
__device__ float    g_cnt[NG];

__device__ __forceinline__ void atomAddF(float* p, float v) {
    unsafeAtomicAdd(p, v);
}

// ---------------- zero the accumulators -------------------------------------
__global__ __launch_bounds__(256) void k_zero() {
    int i = blockIdx.x * 256 + threadIdx.x;
    if (i < NGRP) g_scnt1[i] = 0;
    if (i < NBIN * WNB) g_scnt2[i] = 0;
    if (i < NG * HC) g_pooled[i] = 0.f;
    if (i < NG) g_cnt[i] = 0.f;
}

// ---------------- level-1 sort: edges -> 49 coarse dst groups ---------------
__global__ __launch_bounds__(1024) void k_bin1(const int* __restrict__ ei) {
    __shared__ int s_hist[NGRP];
    __shared__ int s_pref[NGRP];
    __shared__ int s_gbase[NGRP];
    __shared__ unsigned short s_perm[CH1];   // 16 KB
    int t = threadIdx.x;
    int e0 = blockIdx.x * CH1;
    int cnt = NE - e0; if (cnt > CH1) cnt = CH1;

    if (t < NGRP) s_hist[t] = 0;
    __syncthreads();
    for (int i = t; i < cnt; i += 1024)
        atomicAdd(&s_hist[ei[NE + e0 + i] >> 12], 1);
    __syncthreads();
    if (t == 0) {
        int run = 0;
        for (int b = 0; b < NGRP; b++) { s_pref[b] = run; run += s_hist[b]; }
    }
    __syncthreads();
    if (t < NGRP) {
        int c = s_hist[t];
        s_gbase[t] = c ? atomicAdd(&g_scnt1[t], c) : 0;
    }
    __syncthreads();
    if (t < NGRP) s_hist[t] = s_pref[t];     // cursor
    __syncthreads();
    for (int i = t; i < cnt; i += 1024) {
        int d = ei[NE + e0 + i];
        int pos = atomicAdd(&s_hist[d >> 12], 1);
        s_perm[pos] = (unsigned short)i;
    }
    __syncthreads();
    for (int i = t; i < cnt; i += 1024) {
        int idx = s_perm[i];
        int s = ei[e0 + idx];
        int d = ei[NE + e0 + idx];
        int grp = d >> 12;
        int gpos = s_gbase[grp] + (i - s_pref[grp]);
        if (gpos < CAP1)
            g_mid[(size_t)grp * CAP1 + gpos] =
                (unsigned)s | ((unsigned)(d & 4095) << 18);
    }
}

// ---------------- level-2 sort: group chunk -> (fine bin, src window) -------
__global__ __launch_bounds__(1024) void k_bin2() {
    __shared__ int            s_hist[64 * WNB];
    __shared__ int            s_scan[64 * WNB];
    __shared__ unsigned short s_pref[64 * WNB];
    __shared__ unsigned short s_gbase[64 * WNB];
    __shared__ unsigned short s_perm[CH2];   // 16 KB
    int t = threadIdx.x;
    int g = blockIdx.x / CHK2;
    int ch = blockIdx.x % CHK2;
    int total = g_scnt1[g]; if (total > CAP1) total = CAP1;
    int c0 = ch * CH2;
    if (c0 >= total) return;                 // uniform over block
    int cnt = total - c0; if (cnt > CH2) cnt = CH2;
    const unsigned* src = g_mid + (size_t)g * CAP1 + c0;

    if (t < 64 * WNB) s_hist[t] = 0;
    __syncthreads();
    for (int i = t; i < cnt; i += 1024) {
        unsigned p = src[i];
        int key = (int)((p >> 18) >> 6) * WNB + (int)((p & 0x3FFFFu) >= WW);
        atomicAdd(&s_hist[key], 1);
    }
    __syncthreads();
    if (t < 128) s_scan[t] = s_hist[t];
    __syncthreads();
    for (int o = 1; o < 128; o <<= 1) {
        int u = (t >= o && t < 128) ? s_scan[t - o] : 0;
        __syncthreads();
        if (t < 128) s_scan[t] += u;
        __syncthreads();
    }
    if (t < 128) s_pref[t] = (unsigned short)(s_scan[t] - s_hist[t]);
    __syncthreads();
    if (t < 64 * WNB) {
        int c = s_hist[t];
        int gbin = (g << 6) + t / WNB;
        int w = t % WNB;
        s_gbase[t] = (unsigned short)(c ? atomicAdd(&g_scnt2[gbin * WNB + w], c) : 0);
    }
    __syncthreads();
    if (t < 64 * WNB) s_hist[t] = s_pref[t]; // cursor
    __syncthreads();
    for (int i = t; i < cnt; i += 1024) {
        unsigned p = src[i];
        int key = (int)((p >> 18) >> 6) * WNB + (int)((p & 0x3FFFFu) >= WW);
        int pos = atomicAdd(&s_hist[key], 1);
        s_perm[pos] = (unsigned short)i;
    }
    __syncthreads();
    for (int i = t; i < cnt; i += 1024) {
        unsigned p = src[s_perm[i]];
        unsigned ss = p & 0x3FFFFu;
        int d12 = (int)(p >> 18);
        int w = (int)(ss >= WW);
        int key = (d12 >> 6) * WNB + w;
        int gbin = (g << 6) + (d12 >> 6);
        int gpos = (int)s_gbase[key] + (i - (int)s_pref[key]);
        if (gpos < CAPW)
            g_bucket[(size_t)(gbin * WNB + w) * CAPW + gpos] =
                ss | ((unsigned)(d12 & 63) << 18);
    }
}

// ---------------- level-3: per-bin dst-sort + row offsets + dinv ------------
// One block per bin. Counting-sort each (bin,window) list by local dst (64
// keys) into g_bsort; emit per-row segment starts (g_roff) and degrees->dinv.
__global__ __launch_bounds__(256) void k_bin3() {
    __shared__ unsigned s_l[WNB][CAPW];      // 5.6 KB
    __shared__ int s_cnt[128];               // (w*64 + r)
    __shared__ int s_off[128];
    __shared__ int s_len[WNB];
    int t = threadIdx.x;
    int bk = blockIdx.x;
    if (t < WNB) {
        int l = g_scnt2[bk * WNB + t];
        s_len[t] = l < CAPW ? l : CAPW;
    }
    if (t < 128) s_cnt[t] = 0;
    __syncthreads();
    for (int w = 0; w < WNB; w++)
        for (int i = t; i < s_len[w]; i += 256) {
            unsigned u = g_bucket[(size_t)(bk * WNB + w) * CAPW + i];
            s_l[w][i] = u;
            atomicAdd(&s_cnt[w * 64 + (u >> 18)], 1);
        }
    __syncthreads();
    if (t == 0) {
        int run = 0;
        for (int r = 0; r < 64; r++) { s_off[r] = run; run += s_cnt[r]; }
        run = 0;
        for (int r = 0; r < 64; r++) { s_off[64 + r] = run; run += s_cnt[64 + r]; }
    }
    __syncthreads();
    if (t < 128) g_roff[bk * 128 + t] = (unsigned short)s_off[t];
    if (t < 64)
        g_dinv[bk * 64 + t] = rsqrtf((float)(s_cnt[t] + s_cnt[64 + t] + 1));
    __syncthreads();                         // ROUND-10 FIX: dinv reads s_cnt
                                             // (wave 0 reads [64+t]) must complete
                                             // before wave 1 overwrites cursors
    if (t < 128) s_cnt[t] = s_off[t];        // cursor
    __syncthreads();
    for (int w = 0; w < WNB; w++)
        for (int i = t; i < s_len[w]; i += 256) {
            unsigned u = s_l[w][i];
            int pos = atomicAdd(&s_cnt[w * 64 + (u >> 18)], 1);
            g_bsort[(size_t)(bk * WNB + w) * CAPW + pos] = u;
        }
}

// ---------------- h' = (x @ conv_w) * dinv[row] -> fp16 ---------------------
__global__ __launch_bounds__(256) void k_xw(const float* __restrict__ x,
                                            const float* __restrict__ conv_w) {
    __shared__ float s_w[FIN * HC];      // 8 KB
    __shared__ float s_x[64 * 132];      // 33.8 KB
    int t = threadIdx.x;
    for (int i = t; i < FIN * HC; i += 256) s_w[i] = conv_w[i];
    int base = blockIdx.x * 64;
    for (int idx = t; idx < 64 * FIN; idx += 256) {
        int r = idx >> 7, k = idx & 127;
        s_x[r * 132 + k] = x[(size_t)(base + r) * FIN + k];
    }
    __syncthreads();
    int c = t & 15, rg = t >> 4;
    float acc[4] = {0.f, 0.f, 0.f, 0.f};
    for (int k = 0; k < FIN; k++) {
        float w = s_w[k * HC + c];
#pragma unroll
        for (int q = 0; q < 4; q++)
            acc[q] = fmaf(s_x[(rg + 16 * q) * 132 + k], w, acc[q]);
    }
#pragma unroll
    for (int q = 0; q < 4; q++) {
        int row = base + rg + 16 * q;
        g_h[(size_t)row * HC + c] = __float2half(acc[q] * g_dinv[row]);
    }
}

// ---------------- windowed aggregate: 2 launches, ZERO atomics --------------
// Lane-group r (t>>2) owns dst row r; lane q4 (t&3) owns channels 4q4..4q4+3.
// Each group walks its dst-sorted segment, accumulating in VGPRs; one plain
// store at the end. Window W gathers only from W's 3.2 MB L2-resident slice.
template <int W>
__global__ __launch_bounds__(256) void k_aggh(const float* __restrict__ conv_b,
                                              const int* __restrict__ batch) {
    __shared__ unsigned s_lst[CAPW];     // 2.8 KB
    __shared__ float s_agg[64 * SAS];    // 4.25 KB (epilogue only)
    __shared__ float s_pool[16 * 16];
    __shared__ int s_cnt16[16];
    __shared__ int s_len;
    __shared__ int s_b0;
    int t = threadIdx.x;
    int bk = blockIdx.x;
    int base = bk << BSHIFT;

    if (t == 0) {
        int l = g_scnt2[bk * WNB + W];
        s_len = l < CAPW ? l : CAPW;
        if (W == WNB - 1) s_b0 = batch[base];
    }
    if (W == WNB - 1) {
        s_pool[t] = 0.f;
        if (t < 16) s_cnt16[t] = 0;
    }
    __syncthreads();

    int len = s_len;
    const unsigned* lst = g_bsort + (size_t)(bk * WNB + W) * CAPW;
    for (int i = t; i < len; i += 256) s_lst[i] = lst[i];

    int r = t >> 2, q4 = t & 3;
    int off = g_roff[bk * 128 + W * 64 + r];
    int end = (r < 63) ? (int)g_roff[bk * 128 + W * 64 + r + 1] : len;

    float2 accA, accB;
    if (W == 0) {
        accA = make_float2(0.f, 0.f);
        accB = make_float2(0.f, 0.f);
    } else {
        float4 prev = *(const float4*)&g_agg[bk * 1024 + r * 16 + 4 * q4];
        accA = make_float2(prev.x, prev.y);
        accB = make_float2(prev.z, prev.w);
    }
    __syncthreads();

#pragma unroll 4
    for (int i = off; i < end; i++) {
        unsigned p = s_lst[i];
        const __half2* h2 = (const __half2*)
            &g_h[(size_t)(p & 0x3FFFFu) * HC + 4 * q4];
        float2 a = __half22float2(h2[0]);
        float2 b = __half22float2(h2[1]);
        accA.x += a.x; accA.y += a.y;
        accB.x += b.x; accB.y += b.y;
    }

    if (W != WNB - 1) {
        *(float4*)&g_agg[bk * 1024 + r * 16 + 4 * q4] =
            make_float4(accA.x, accA.y, accB.x, accB.y);
        return;
    }

    // ---- last window: self-loop + bias + relu + fused mean-pool ----
    s_agg[r * SAS + 4 * q4 + 0] = accA.x;
    s_agg[r * SAS + 4 * q4 + 1] = accA.y;
    s_agg[r * SAS + 4 * q4 + 2] = accB.x;
    s_agg[r * SAS + 4 * q4 + 3] = accB.y;
    __syncthreads();

    int c = t & 15;
#pragma unroll
    for (int qq = 0; qq < 4; qq++) {
        int ln = (t >> 4) + qq * 16;     // local node 0..63
        int node = base + ln;            // NN = 3125*64 exactly
        float di = g_dinv[node];
        float hself = __half2float(g_h[(size_t)node * HC + c]);
        float val = di * (s_agg[ln * SAS + c] + hself) + conv_b[c];
        float rv = val > 0.f ? val : 0.f;
        int b = batch[node];
        int slot = b - s_b0;
        if (slot < 16) {
            atomicAdd(&s_pool[slot * 16 + c], rv);
            if (c == 0) atomicAdd(&s_cnt16[slot], 1);
        } else {                         // astronomically rare
            atomAddF(&g_pooled[(size_t)b * HC + c], rv);
            if (c == 0) atomAddF(&g_cnt[b], 1.f);
        }
    }
    __syncthreads();

    int slot2 = t >> 4;
    if (s_cnt16[slot2] > 0)
        atomAddF(&g_pooled[(size_t)(s_b0 + slot2) * HC + c], s_pool[t]);
    if (t < 16 && s_cnt16[t] > 0)
        atomAddF(&g_cnt[s_b0 + t], (float)s_cnt16[t]);
}

// ---------------- MLP + heads (f32 output) ----------------------------------
__global__ __launch_bounds__(256) void k_mlp(const float* __restrict__ w1,
                                             const float* __restrict__ b1,
                                             const float* __restrict__ w2,
                                             const float* __restrict__ b2,
                                             const float* __restrict__ head_w,
                                             const float* __restrict__ head_b,
                                             float* __restrict__ out) {
    __shared__ float s_w1[HC * D1];
    __shared__ float s_b1[D1];
    __shared__ float s_w2[D1 * D1];
    __shared__ float s_b2[D1];
    __shared__ float s_hw[NM * D1 * NA];
    __shared__ float s_hb[NM * NA];
    __shared__ float s_p[4][HC];
    __shared__ float s_g1[4][D1];
    __shared__ float s_g2[4][D1];

    int tid = threadIdx.x;
    for (int i = tid; i < HC * D1; i += 256) s_w1[i] = w1[i];
    for (int i = tid; i < D1; i += 256) { s_b1[i] = b1[i]; s_b2[i] = b2[i]; }
    for (int i = tid; i < D1 * D1; i += 256) s_w2[i] = w2[i];
    for (int i = tid; i < NM * D1 * NA; i += 256) s_hw[i] = head_w[i];
    for (int i = tid; i < NM * NA; i += 256) s_hb[i] = head_b[i];

    int grp = tid >> 6, lane = tid & 63;
    int g = blockIdx.x * 4 + grp;
    if (lane < HC) {
        float cc = g_cnt[g];
        s_p[grp][lane] = g_pooled[g * HC + lane] / fmaxf(cc, 1.0f);
    }
    __syncthreads();
    {
        float a = s_b1[lane];
#pragma unroll
        for (int c = 0; c < HC; c++) a = fmaf(s_p[grp][c], s_w1[c * D1 + lane], a);
        s_g1[grp][lane] = a > 0.f ? a : expm1f(a);
    }
    __syncthreads();
    {
        float a = s_b2[lane];
#pragma unroll
        for (int d = 0; d < D1; d++) a = fmaf(s_g1[grp][d], s_w2[d * D1 + lane], a);
        s_g2[grp][lane] = a > 0.f ? a : expm1f(a);
    }
    __syncthreads();
    for (int idx = lane; idx < NM * NA; idx += 64) {
        int m = idx >> 3, a = idx & 7;
        float v = s_hb[idx];
#pragma unroll
        for (int d = 0; d < D1; d++)
            v = fmaf(s_g2[grp][d], s_hw[m * (D1 * NA) + d * NA + a], v);
        out[(size_t)g * (NM * NA) + idx] = v;
    }
}

extern "C" void kernel_launch(void* const* d_in, const int* in_sizes, int n_in,
                              void* d_out, int out_size, void* d_ws, size_t ws_size,
                              hipStream_t stream) {
    const float* x      = (const float*)d_in[0];
    const int*   ei     = (const int*)d_in[1];
    const int*   batch  = (const int*)d_in[2];
    const float* conv_w = (const float*)d_in[3];
    const float* conv_b = (const float*)d_in[4];
    const float* w1     = (const float*)d_in[5];
    const float* b1     = (const float*)d_in[6];
    const float* w2     = (const float*)d_in[7];
    const float* b2     = (const float*)d_in[8];
    const float* head_w = (const float*)d_in[9];
    const float* head_b = (const float*)d_in[10];
    float* out = (float*)d_out;

    k_zero<<<NBLK, 256, 0, stream>>>();
    k_bin1<<<NB1, 1024, 0, stream>>>(ei);
    k_bin2<<<NGRP * CHK2, 1024, 0, stream>>>();
    k_bin3<<<NBIN, 256, 0, stream>>>();
    k_xw<<<NN / 64, 256, 0, stream>>>(x, conv_w);
    k_aggh<0><<<NBIN, 256, 0, stream>>>(conv_b, batch);
    k_aggh<1><<<NBIN, 256, 0, stream>>>(conv_b, batch);
    k_mlp<<<NG / 4, 256, 0, stream>>>(w1, b1, w2, b2, head_w, head_b, out);
}